// Round 1
// baseline (169.577 us; speedup 1.0000x reference)
//
#include <hip/hip_runtime.h>
#include <hip/hip_bf16.h>

// Problem constants
#define BQ   8
#define HW   16384        // 128*128
#define CIN  64
#define C3   192
#define KPB  64           // reduce-kernel blocks per batch
#define TPB  4            // main-kernel 64-pixel tiles per block

typedef __attribute__((ext_vector_type(8))) short short8;   // 8 bf16 (4 VGPR)
typedef __attribute__((ext_vector_type(4))) float f32x4;    // MFMA accumulator

__device__ __forceinline__ ushort f2bf(float f) {
    // round-to-nearest-even fp32 -> bf16 (inputs are finite normals)
    uint u = __float_as_uint(f);
    u += 0x7fffu + ((u >> 16) & 1u);
    return (ushort)(u >> 16);
}

// ---------------------------------------------------------------------------
// K1: per-batch channel sums. partials[b][kblk][c3], c3 = 3*channel + tensor
// ---------------------------------------------------------------------------
__global__ __launch_bounds__(256) void k_reduce(const float* __restrict__ t1,
                                                const float* __restrict__ t2,
                                                const float* __restrict__ t3,
                                                float* __restrict__ partials) {
    const int bid  = blockIdx.x;
    const int b    = bid >> 6;          // batch
    const int kblk = bid & 63;          // 64 blocks per batch
    const size_t base = (size_t)b * (size_t)(HW * CIN) + (size_t)kblk * 16384;
    const float4* s0 = (const float4*)(t1 + base);
    const float4* s1 = (const float4*)(t2 + base);
    const float4* s2 = (const float4*)(t3 + base);
    const int tid = threadIdx.x;

    float acc[3][4] = {{0.f,0.f,0.f,0.f},{0.f,0.f,0.f,0.f},{0.f,0.f,0.f,0.f}};
#pragma unroll
    for (int i = 0; i < 16; ++i) {
        const int idx = i * 256 + tid;               // float4 index; c0=(tid&15)*4 fixed
        float4 v0 = s0[idx];
        float4 v1 = s1[idx];
        float4 v2 = s2[idx];
        acc[0][0] += v0.x; acc[0][1] += v0.y; acc[0][2] += v0.z; acc[0][3] += v0.w;
        acc[1][0] += v1.x; acc[1][1] += v1.y; acc[1][2] += v1.z; acc[1][3] += v1.w;
        acc[2][0] += v2.x; acc[2][1] += v2.y; acc[2][2] += v2.z; acc[2][3] += v2.w;
    }
    // lanes l, l+16, l+32, l+48 share the same channel group -> butterfly
#pragma unroll
    for (int t = 0; t < 3; ++t)
#pragma unroll
        for (int j = 0; j < 4; ++j) {
            float v = acc[t][j];
            v += __shfl_xor(v, 16);
            v += __shfl_xor(v, 32);
            acc[t][j] = v;
        }

    __shared__ float red[4][C3];
    const int lane = tid & 63, wave = tid >> 6;
    if (lane < 16) {
#pragma unroll
        for (int t = 0; t < 3; ++t)
#pragma unroll
            for (int j = 0; j < 4; ++j)
                red[wave][3 * (lane * 4 + j) + t] = acc[t][j];
    }
    __syncthreads();
    if (tid < C3) {
        float v = red[0][tid] + red[1][tid] + red[2][tid] + red[3][tid];
        partials[(size_t)(b * KPB + kblk) * C3 + tid] = v;
    }
}

// ---------------------------------------------------------------------------
// K2: finish mean, SE dense layers (fp32), emit folded bf16 weights
//     wbT[b][f][k'] with k' = tensor*64 + c  (so K3 LDS staging is linear)
// ---------------------------------------------------------------------------
__global__ __launch_bounds__(256) void k_se(const float* __restrict__ partials,
                                            const float* __restrict__ w_se1,
                                            const float* __restrict__ w_se2,
                                            const float* __restrict__ w_conv,
                                            ushort* __restrict__ wbT) {
    const int b = blockIdx.x, tid = threadIdx.x;
    __shared__ float s_lds[C3];
    __shared__ float h_lds[12];
    __shared__ float sig_lds[C3];

    if (tid < C3) {
        float s = 0.f;
        const float* p = partials + (size_t)b * KPB * C3 + tid;
        for (int k = 0; k < KPB; ++k) s += p[k * C3];
        s_lds[tid] = s * (1.f / 16384.f);
    }
    __syncthreads();
    if (tid < 12) {
        float h = 0.f;
        for (int j = 0; j < C3; ++j) h += s_lds[j] * w_se1[j * 12 + tid];
        h_lds[tid] = fmaxf(h, 0.f);
    }
    __syncthreads();
    if (tid < C3) {
        float z = 0.f;
#pragma unroll
        for (int i = 0; i < 12; ++i) z += h_lds[i] * w_se2[i * C3 + tid];
        sig_lds[tid] = 1.f / (1.f + expf(-z));
    }
    __syncthreads();
    if (tid < C3) {
        const int c = tid & 63, t = tid >> 6;
        const int c3 = 3 * c + t;                 // original interleaved index
        const float g = sig_lds[c3];
        ushort* dst = wbT + (size_t)b * CIN * C3; // [64][192] bf16
        for (int f = 0; f < CIN; ++f)
            dst[f * C3 + tid] = f2bf(g * w_conv[c3 * CIN + f]);
    }
}

// ---------------------------------------------------------------------------
// K3: gated conv via bf16 MFMA. Block = 4 waves, 64-pixel tiles, N=64 fixed.
// ---------------------------------------------------------------------------
__global__ __launch_bounds__(256) void k_main(const float* __restrict__ t1,
                                              const float* __restrict__ t2,
                                              const float* __restrict__ t3,
                                              const ushort* __restrict__ wbT,
                                              const float* __restrict__ b_conv,
                                              float* __restrict__ out) {
    __shared__ ushort xs[64 * 200];   // x tile  [64 pixels][192 k'] pad->200
    __shared__ ushort wt[64 * 200];   // weights [64 f     ][192 k'] pad->200

    const int bid  = blockIdx.x;
    const int b    = bid >> 6;
    const int kblk = bid & 63;
    const int tid  = threadIdx.x;
    const int lane = tid & 63, wave = tid >> 6;
    const int l16  = lane & 15, lhi = lane >> 4;

    // stage per-batch weights once
    {
        const uint2* src = (const uint2*)(wbT + (size_t)b * CIN * C3);
#pragma unroll
        for (int i = 0; i < 12; ++i) {
            int ch  = i * 256 + tid;      // 0..3071 8-byte chunks (48 per row)
            int row = ch / 48, col8 = ch % 48;
            *(uint2*)&wt[row * 200 + col8 * 4] = src[ch];
        }
    }

    float bias[4];
#pragma unroll
    for (int ft = 0; ft < 4; ++ft) bias[ft] = b_conv[ft * 16 + l16];

    for (int j = 0; j < TPB; ++j) {
        const int tile = kblk + j * 64;                 // 0..255 within batch
        const size_t pbase = (size_t)b * HW + (size_t)tile * 64;
        __syncthreads();   // previous tile's LDS reads done
        // stage x: 64 pixels x 64 c of each tensor, contiguous 16KB each
        const float4* src0 = (const float4*)(t1 + pbase * CIN);
        const float4* src1 = (const float4*)(t2 + pbase * CIN);
        const float4* src2 = (const float4*)(t3 + pbase * CIN);
#pragma unroll
        for (int t = 0; t < 3; ++t) {
            const float4* s = (t == 0) ? src0 : (t == 1) ? src1 : src2;
#pragma unroll
            for (int i = 0; i < 4; ++i) {
                int idx = i * 256 + tid;                // float4 index 0..1023
                float4 v = s[idx];
                int pix = idx >> 4, c = (idx & 15) * 4;
                ushort4 pk;
                pk.x = f2bf(v.x); pk.y = f2bf(v.y);
                pk.z = f2bf(v.z); pk.w = f2bf(v.w);
                *(ushort4*)&xs[pix * 200 + t * 64 + c] = pk;
            }
        }
        __syncthreads();

        f32x4 acc[4];
#pragma unroll
        for (int ft = 0; ft < 4; ++ft) acc[ft] = (f32x4){0.f, 0.f, 0.f, 0.f};
        const int arow = wave * 16 + l16;
        const int ko   = lhi * 8;
#pragma unroll
        for (int kt = 0; kt < 6; ++kt) {
            short8 a = *(const short8*)&xs[arow * 200 + kt * 32 + ko];
#pragma unroll
            for (int ft = 0; ft < 4; ++ft) {
                short8 bb = *(const short8*)&wt[(ft * 16 + l16) * 200 + kt * 32 + ko];
                acc[ft] = __builtin_amdgcn_mfma_f32_16x16x32_bf16(a, bb, acc[ft], 0, 0, 0);
            }
        }
        // epilogue: D col = l16 (f), row = lhi*4 + r (pixel)
        const size_t obase = ((size_t)b * HW + (size_t)tile * 64 + wave * 16) * CIN;
#pragma unroll
        for (int ft = 0; ft < 4; ++ft) {
#pragma unroll
            for (int r = 0; r < 4; ++r) {
                float v = acc[ft][r] + bias[ft];
                v = fmaxf(v, 0.f);
                out[obase + (size_t)(lhi * 4 + r) * CIN + ft * 16 + l16] = v;
            }
        }
    }
}

extern "C" void kernel_launch(void* const* d_in, const int* in_sizes, int n_in,
                              void* d_out, int out_size, void* d_ws, size_t ws_size,
                              hipStream_t stream) {
    (void)in_sizes; (void)n_in; (void)out_size; (void)ws_size;
    const float* t1     = (const float*)d_in[0];
    const float* t2     = (const float*)d_in[1];
    const float* t3     = (const float*)d_in[2];
    const float* w_se1  = (const float*)d_in[3];
    const float* w_se2  = (const float*)d_in[4];
    const float* w_conv = (const float*)d_in[5];
    const float* b_conv = (const float*)d_in[6];
    float* out = (float*)d_out;

    float*  partials = (float*)d_ws;                              // 512*192*4 = 393216 B
    ushort* wbT      = (ushort*)((char*)d_ws + 512 * C3 * 4);     // 8*64*192*2 = 196608 B

    k_reduce<<<dim3(BQ * KPB), dim3(256), 0, stream>>>(t1, t2, t3, partials);
    k_se<<<dim3(BQ), dim3(256), 0, stream>>>(partials, w_se1, w_se2, w_conv, wbT);
    k_main<<<dim3(BQ * KPB), dim3(256), 0, stream>>>(t1, t2, t3, wbT, b_conv, out);
}